// Round 1
// baseline (1786.764 us; speedup 1.0000x reference)
//
#include <hip/hip_runtime.h>
#include <hip/hip_bf16.h>
#include <math.h>

#define L_SEQ 1024
#define TWO_L 2048
#define NHEAD 16
#define HD 64
#define DM 1024
#define BATCH 2

// ---------------- kernel 1: sinusoid table pe[2048][64] ----------------
__global__ void pe_kernel(float* __restrict__ pe) {
  int l = blockIdx.x;          // 0..2047
  int d = threadIdx.x;         // 0..63
  float posval = (float)(l - L_SEQ);          // l - 1024
  int i = d & 31;
  float freq = expf(-(float)i * 0.2971077539347156f);   // ln(10000)/31
  float ang = posval * freq;
  pe[l * HD + d] = (d < 32) ? sinf(ang) : cosf(ang);
}

// ---------------- kernel 1b: D[h][l] = r_w_bias[h] . pe[l] ----------------
__global__ void dmat_kernel(const float* __restrict__ rw, const float* __restrict__ pe,
                            float* __restrict__ Dm) {
  int idx = blockIdx.x * blockDim.x + threadIdx.x;   // h*2048 + l
  int h = idx >> 11;
  int l = idx & (TWO_L - 1);
  float s = 0.f;
#pragma unroll
  for (int d = 0; d < HD; ++d) s = fmaf(rw[h * HD + d], pe[l * HD + d], s);
  Dm[idx] = s;
}

// ---------------- kernel 2: qv[2048][2048] = x[2048][1024] @ W[2048][1024]^T ----------------
__global__ __launch_bounds__(256) void qv_gemm(const float* __restrict__ A,
                                               const float* __restrict__ B,
                                               float* __restrict__ C) {
  __shared__ float sA[16][68];
  __shared__ float sB[16][68];
  int tid = threadIdx.x;
  int m0 = blockIdx.y * 64, n0 = blockIdx.x * 64;
  int row = tid >> 2;
  int kp = (tid & 3) * 4;
  int ty = tid >> 4, tx = tid & 15;
  float c[4][4] = {};
  for (int k0 = 0; k0 < 1024; k0 += 16) {
    float4 a4 = *(const float4*)(A + (size_t)(m0 + row) * 1024 + k0 + kp);
    float4 b4 = *(const float4*)(B + (size_t)(n0 + row) * 1024 + k0 + kp);
    sA[kp + 0][row] = a4.x; sA[kp + 1][row] = a4.y; sA[kp + 2][row] = a4.z; sA[kp + 3][row] = a4.w;
    sB[kp + 0][row] = b4.x; sB[kp + 1][row] = b4.y; sB[kp + 2][row] = b4.z; sB[kp + 3][row] = b4.w;
    __syncthreads();
#pragma unroll
    for (int kk = 0; kk < 16; ++kk) {
      float4 a4r = *(const float4*)&sA[kk][ty * 4];
      float4 b4r = *(const float4*)&sB[kk][tx * 4];
      float a[4] = {a4r.x, a4r.y, a4r.z, a4r.w};
      float b[4] = {b4r.x, b4r.y, b4r.z, b4r.w};
#pragma unroll
      for (int i = 0; i < 4; ++i)
#pragma unroll
        for (int j = 0; j < 4; ++j) c[i][j] = fmaf(a[i], b[j], c[i][j]);
    }
    __syncthreads();
  }
#pragma unroll
  for (int i = 0; i < 4; ++i) {
    float4 v = {c[i][0], c[i][1], c[i][2], c[i][3]};
    *(float4*)(C + (size_t)(m0 + ty * 4 + i) * 2048 + n0 + tx * 4) = v;
  }
}

// ---------------- kernel 2b: E'[bh][q][j] = q . pe[j] + D[h][j]  (bf16) ----------------
__global__ __launch_bounds__(256) void e_gemm(const float* __restrict__ qv,
                                              const float* __restrict__ pe,
                                              const float* __restrict__ Dm,
                                              __hip_bfloat16* __restrict__ E) {
  __shared__ float sA[16][68];
  __shared__ float sB[16][68];
  int tid = threadIdx.x;
  int bh = blockIdx.z;
  int b = bh >> 4, h = bh & 15;
  int m0 = blockIdx.y * 64, n0 = blockIdx.x * 64;
  int row = tid >> 2;
  int kp = (tid & 3) * 4;
  int ty = tid >> 4, tx = tid & 15;
  float c[4][4] = {};
  for (int k0 = 0; k0 < 64; k0 += 16) {
    float4 a4 = *(const float4*)(qv + (size_t)(b * L_SEQ + m0 + row) * 2048 + h * HD + k0 + kp);
    float4 b4 = *(const float4*)(pe + (size_t)(n0 + row) * HD + k0 + kp);
    sA[kp + 0][row] = a4.x; sA[kp + 1][row] = a4.y; sA[kp + 2][row] = a4.z; sA[kp + 3][row] = a4.w;
    sB[kp + 0][row] = b4.x; sB[kp + 1][row] = b4.y; sB[kp + 2][row] = b4.z; sB[kp + 3][row] = b4.w;
    __syncthreads();
#pragma unroll
    for (int kk = 0; kk < 16; ++kk) {
      float4 a4r = *(const float4*)&sA[kk][ty * 4];
      float4 b4r = *(const float4*)&sB[kk][tx * 4];
      float a[4] = {a4r.x, a4r.y, a4r.z, a4r.w};
      float b[4] = {b4r.x, b4r.y, b4r.z, b4r.w};
#pragma unroll
      for (int i = 0; i < 4; ++i)
#pragma unroll
        for (int j = 0; j < 4; ++j) c[i][j] = fmaf(a[i], b[j], c[i][j]);
    }
    __syncthreads();
  }
#pragma unroll
  for (int i = 0; i < 4; ++i) {
    int q = m0 + ty * 4 + i;
    int col = n0 + tx * 4;
    union { unsigned short u[4]; uint2 v2; } pk;
#pragma unroll
    for (int j = 0; j < 4; ++j) {
      float val = c[i][j] + Dm[h * TWO_L + col + j];
      __hip_bfloat16 bf = __float2bfloat16(val);
      pk.u[j] = *reinterpret_cast<unsigned short*>(&bf);
    }
    *reinterpret_cast<uint2*>(E + ((size_t)bh * L_SEQ + q) * TWO_L + col) = pk.v2;
  }
}

// ---------------- kernel 3: fused scores + shift-gather + softmax + PV ----------------
// block = 256 threads, 8 q-rows; grid (L/8, B*H)
__global__ __launch_bounds__(256) void attn_kernel(const float* __restrict__ x,
                                                   const int* __restrict__ mask,
                                                   const float* __restrict__ qv,
                                                   const __hip_bfloat16* __restrict__ E,
                                                   const float* __restrict__ rr,
                                                   float* __restrict__ out) {
  __shared__ float sc[8 * L_SEQ];     // 32 KB scores
  __shared__ float qb[8 * HD];        // q + r_r_bias
  __shared__ float tile[64 * 68];     // v tile for PV (17.4 KB)
  __shared__ float sinv[8];

  int tid = threadIdx.x;
  int q0 = blockIdx.x * 8;
  int bh = blockIdx.y;
  int b = bh >> 4, h = bh & 15;

  // load q rows (+bias)
#pragma unroll
  for (int i = 0; i < 2; ++i) {
    int idx = tid + i * 256;          // 0..511 = r*64 + d
    int r = idx >> 6, d = idx & 63;
    qb[idx] = qv[(size_t)(b * L_SEQ + q0 + r) * 2048 + h * HD + d] + rr[h * HD + d];
  }
  __syncthreads();

  // ---- phase B: scores. each thread owns 2 k-rows per pass (2 passes) ----
  for (int kb = 0; kb < 2; ++kb) {
    int k1 = kb * 512 + tid;
    int k2 = k1 + 256;
    const float* xr1 = x + (size_t)(b * L_SEQ + k1) * DM + h * HD;
    const float* xr2 = x + (size_t)(b * L_SEQ + k2) * DM + h * HD;
    float acc1[8], acc2[8];
#pragma unroll
    for (int r = 0; r < 8; ++r) { acc1[r] = 0.f; acc2[r] = 0.f; }
#pragma unroll
    for (int d4 = 0; d4 < HD; d4 += 4) {
      float4 xv1 = *(const float4*)(xr1 + d4);
      float4 xv2 = *(const float4*)(xr2 + d4);
#pragma unroll
      for (int r = 0; r < 8; ++r) {
        float q0v = qb[r * HD + d4 + 0], q1v = qb[r * HD + d4 + 1];
        float q2v = qb[r * HD + d4 + 2], q3v = qb[r * HD + d4 + 3];
        acc1[r] = fmaf(q0v, xv1.x, acc1[r]); acc2[r] = fmaf(q0v, xv2.x, acc2[r]);
        acc1[r] = fmaf(q1v, xv1.y, acc1[r]); acc2[r] = fmaf(q1v, xv2.y, acc2[r]);
        acc1[r] = fmaf(q2v, xv1.z, acc1[r]); acc2[r] = fmaf(q2v, xv2.z, acc2[r]);
        acc1[r] = fmaf(q3v, xv1.w, acc1[r]); acc2[r] = fmaf(q3v, xv2.w, acc2[r]);
      }
    }
    int mv1 = mask[b * L_SEQ + k1];
    int mv2 = mask[b * L_SEQ + k2];
#pragma unroll
    for (int r = 0; r < 8; ++r) {
      int q = q0 + r;
      // k1
      float s = acc1[r];
      if (k1 != q - 1) {
        int col, qe;
        if (k1 >= q) { col = k1 - q; qe = q; } else { col = TWO_L + 1 - q + k1; qe = q - 1; }
        s += __bfloat162float(E[((size_t)bh * L_SEQ + qe) * TWO_L + col]);
      }
      if (mv1 == 0) s = -1e30f;
      sc[r * L_SEQ + k1] = s;
      // k2
      float t = acc2[r];
      if (k2 != q - 1) {
        int col, qe;
        if (k2 >= q) { col = k2 - q; qe = q; } else { col = TWO_L + 1 - q + k2; qe = q - 1; }
        t += __bfloat162float(E[((size_t)bh * L_SEQ + qe) * TWO_L + col]);
      }
      if (mv2 == 0) t = -1e30f;
      sc[r * L_SEQ + k2] = t;
    }
  }
  __syncthreads();

  // ---- phase C: softmax, one 32-lane group per row ----
  {
    int r = tid >> 5, l32 = tid & 31;
    float m = -1e30f;
    for (int k = l32; k < L_SEQ; k += 32) m = fmaxf(m, sc[r * L_SEQ + k]);
#pragma unroll
    for (int off = 16; off; off >>= 1) m = fmaxf(m, __shfl_xor(m, off, 32));
    float ssum = 0.f;
    for (int k = l32; k < L_SEQ; k += 32) {
      float p = __expf(sc[r * L_SEQ + k] - m);
      sc[r * L_SEQ + k] = p;
      ssum += p;
    }
#pragma unroll
    for (int off = 16; off; off >>= 1) ssum += __shfl_xor(ssum, off, 32);
    if (l32 == 0) sinv[r] = 1.0f / ssum;
  }

  // ---- phase D: PV with LDS-staged v tiles ----
  int d = tid & 63, r2 = tid >> 6;    // rows r2 and r2+4
  float o0 = 0.f, o1 = 0.f;
  for (int k0 = 0; k0 < L_SEQ; k0 += 64) {
    __syncthreads();
#pragma unroll
    for (int i = 0; i < 4; ++i) {
      int idx = tid + i * 256;
      int kk = idx >> 4, f4 = (idx & 15) * 4;
      float4 v4 = *(const float4*)(qv + (size_t)(b * L_SEQ + k0 + kk) * 2048 + DM + h * HD + f4);
      *(float4*)&tile[kk * 68 + f4] = v4;
    }
    __syncthreads();
#pragma unroll
    for (int kk = 0; kk < 64; ++kk) {
      float vv = tile[kk * 68 + d];
      o0 = fmaf(sc[r2 * L_SEQ + k0 + kk], vv, o0);
      o1 = fmaf(sc[(r2 + 4) * L_SEQ + k0 + kk], vv, o1);
    }
  }
  out[(size_t)(b * L_SEQ + q0 + r2) * DM + h * HD + d] = o0 * sinv[r2];
  out[(size_t)(b * L_SEQ + q0 + r2 + 4) * DM + h * HD + d] = o1 * sinv[r2 + 4];
}

extern "C" void kernel_launch(void* const* d_in, const int* in_sizes, int n_in,
                              void* d_out, int out_size, void* d_ws, size_t ws_size,
                              hipStream_t stream) {
  const float* x = (const float*)d_in[0];
  const int* mask = (const int*)d_in[1];
  const float* W = (const float*)d_in[2];
  const float* rr = (const float*)d_in[3];
  const float* rw = (const float*)d_in[4];
  float* out = (float*)d_out;

  float* ws = (float*)d_ws;
  float* pe = ws;                                   // 2048*64
  float* Dm = pe + (size_t)TWO_L * HD;              // 16*2048
  float* qv = Dm + (size_t)NHEAD * TWO_L;           // 2048*2048
  __hip_bfloat16* E = (__hip_bfloat16*)(qv + (size_t)2048 * 2048);  // 32*1024*2048 bf16

  pe_kernel<<<TWO_L, HD, 0, stream>>>(pe);
  dmat_kernel<<<(NHEAD * TWO_L) / 256, 256, 0, stream>>>(rw, pe, Dm);
  qv_gemm<<<dim3(32, 32), 256, 0, stream>>>(x, W, qv);
  e_gemm<<<dim3(32, 16, 32), 256, 0, stream>>>(qv, pe, Dm, E);
  attn_kernel<<<dim3(L_SEQ / 8, BATCH * NHEAD), 256, 0, stream>>>(x, mask, qv, E, rr, out);
}

// Round 2
// 153.643 us; speedup vs baseline: 11.6293x; 11.6293x over previous
//
#include <hip/hip_runtime.h>
#include <hip/hip_bf16.h>
#include <math.h>

#define L_SEQ 1024
#define TWO_L 2048
#define NHEAD 16
#define HD 64
#define DM 1024
#define BATCH 2

typedef _Float16 f16;
typedef _Float16 f16x4 __attribute__((ext_vector_type(4)));
typedef _Float16 f16x8 __attribute__((ext_vector_type(8)));
typedef float f32x4 __attribute__((ext_vector_type(4)));

// Load an 8-elem f16 MFMA operand fragment: 4 contiguous halves at p, 4 at p+16
// (k = (lane>>4)*4 + (j&3) + 16*(j>>2) layout for 16x16x32).
__device__ __forceinline__ f16x8 ld8(const f16* p) {
  f16x4 lo = *(const f16x4*)p;
  f16x4 hi = *(const f16x4*)(p + 16);
  f16x8 r;
  r[0] = lo[0]; r[1] = lo[1]; r[2] = lo[2]; r[3] = lo[3];
  r[4] = hi[0]; r[5] = hi[1]; r[6] = hi[2]; r[7] = hi[3];
  return r;
}

// ---------------- f32 -> f16 convert ----------------
__global__ __launch_bounds__(256) void cvt_kernel(const float* __restrict__ src,
                                                  f16* __restrict__ dst) {
  int i = (blockIdx.x * 256 + threadIdx.x) * 4;
  float4 v = *(const float4*)(src + i);
  f16x4 o = {(f16)v.x, (f16)v.y, (f16)v.z, (f16)v.w};
  *(f16x4*)(dst + i) = o;
}

// ---------------- sinusoid table pe[2048][64] (f32 + f16) ----------------
__global__ void pe_kernel(float* __restrict__ pe, f16* __restrict__ peh) {
  int l = blockIdx.x;          // 0..2047
  int d = threadIdx.x;         // 0..63
  float posval = (float)(l - L_SEQ);
  int i = d & 31;
  float freq = expf(-(float)i * 0.2971077539347156f);   // ln(10000)/31
  float ang = posval * freq;
  float v = (d < 32) ? sinf(ang) : cosf(ang);
  pe[l * HD + d] = v;
  peh[l * HD + d] = (f16)v;
}

// ---------------- D[h][l] = r_w_bias[h] . pe[l] ----------------
__global__ __launch_bounds__(256) void dmat_kernel(const float* __restrict__ rw,
                                                   const float* __restrict__ pe,
                                                   float* __restrict__ Dm) {
  int idx = blockIdx.x * 256 + threadIdx.x;   // h*2048 + l
  int h = idx >> 11;
  int l = idx & (TWO_L - 1);
  float s = 0.f;
#pragma unroll
  for (int d = 0; d < HD; ++d) s = fmaf(rw[h * HD + d], pe[l * HD + d], s);
  Dm[idx] = s;
}

// ---------------- zero the shifted diagonal F[bh][q][q-1] ----------------
__global__ __launch_bounds__(256) void fzero_kernel(f16* __restrict__ F) {
  int idx = blockIdx.x * 256 + threadIdx.x;   // bh*1024 + q
  int bh = idx >> 10, q = idx & 1023;
  if (q >= 1) F[((size_t)bh * L_SEQ + q) * L_SEQ + q - 1] = (f16)0.f;
}

// ---------------- qv GEMM: qv[2048][2048] = xh @ Wh^T (f16 MFMA) ----------------
// also writes vT[b][h][d][l] for the v half (n >= 1024)
__global__ __launch_bounds__(256) void qv_mfma(const f16* __restrict__ xh,
                                               const f16* __restrict__ Wh,
                                               f16* __restrict__ qvh,
                                               f16* __restrict__ vT) {
  __shared__ f16 As[64 * 72];
  __shared__ f16 Bs[64 * 72];
  int tid = threadIdx.x;
  int w = tid >> 6, lane = tid & 63, g = lane >> 4, li = lane & 15;
  int m0 = blockIdx.y * 64, n0 = blockIdx.x * 64;

  f32x4 s[4];
#pragma unroll
  for (int i = 0; i < 4; ++i) s[i] = {0.f, 0.f, 0.f, 0.f};

  int r = tid >> 2, c = (tid & 3) * 16;
  for (int k0 = 0; k0 < 1024; k0 += 64) {
    __syncthreads();
    const f16* sa = xh + (size_t)(m0 + r) * 1024 + k0 + c;
    *(f16x8*)&As[r * 72 + c] = *(const f16x8*)sa;
    *(f16x8*)&As[r * 72 + c + 8] = *(const f16x8*)(sa + 8);
    const f16* sb = Wh + (size_t)(n0 + r) * 1024 + k0 + c;
    *(f16x8*)&Bs[r * 72 + c] = *(const f16x8*)sb;
    *(f16x8*)&Bs[r * 72 + c + 8] = *(const f16x8*)(sb + 8);
    __syncthreads();
#pragma unroll
    for (int kc = 0; kc < 2; ++kc) {
      f16x8 a = ld8(&As[(w * 16 + li) * 72 + kc * 32 + g * 4]);
#pragma unroll
      for (int nf = 0; nf < 4; ++nf) {
        f16x8 b = ld8(&Bs[(nf * 16 + li) * 72 + kc * 32 + g * 4]);
        s[nf] = __builtin_amdgcn_mfma_f32_16x16x32_f16(a, b, s[nf], 0, 0, 0);
      }
    }
  }
#pragma unroll
  for (int nf = 0; nf < 4; ++nf) {
    int n = n0 + nf * 16 + li;
#pragma unroll
    for (int rr2 = 0; rr2 < 4; ++rr2) {
      int m = m0 + w * 16 + g * 4 + rr2;
      f16 val = (f16)s[nf][rr2];
      qvh[(size_t)m * 2048 + n] = val;
      if (n >= 1024) {
        int b_ = m >> 10, ls = m & 1023, hd = n - 1024;
        vT[((size_t)(b_ * 16 + (hd >> 6)) * 64 + (hd & 63)) * 1024 + ls] = val;
      }
    }
  }
}

// ---------------- F GEMM: B_[q][j] = q.pe_j + D[h][j], scatter to shifted F ----------------
__global__ __launch_bounds__(256) void f_gemm(const f16* __restrict__ qvh,
                                              const f16* __restrict__ peh,
                                              const float* __restrict__ Dm,
                                              f16* __restrict__ F) {
  __shared__ f16 Qs[64 * 72];
  __shared__ f16 Ps[64 * 72];
  int tid = threadIdx.x;
  int w = tid >> 6, lane = tid & 63, g = lane >> 4, li = lane & 15;
  int bh = blockIdx.z, b = bh >> 4, h = bh & 15;
  int q0 = blockIdx.y * 64, n0 = blockIdx.x * 64;

  int r = tid >> 2, c = (tid & 3) * 16;
  const f16* sq = qvh + (size_t)(b * L_SEQ + q0 + r) * 2048 + h * HD + c;
  *(f16x8*)&Qs[r * 72 + c] = *(const f16x8*)sq;
  *(f16x8*)&Qs[r * 72 + c + 8] = *(const f16x8*)(sq + 8);
  const f16* sp = peh + (size_t)(n0 + r) * HD + c;
  *(f16x8*)&Ps[r * 72 + c] = *(const f16x8*)sp;
  *(f16x8*)&Ps[r * 72 + c + 8] = *(const f16x8*)(sp + 8);
  __syncthreads();

  f32x4 s[4];
#pragma unroll
  for (int i = 0; i < 4; ++i) s[i] = {0.f, 0.f, 0.f, 0.f};
#pragma unroll
  for (int kc = 0; kc < 2; ++kc) {
    f16x8 a = ld8(&Qs[(w * 16 + li) * 72 + kc * 32 + g * 4]);
#pragma unroll
    for (int nf = 0; nf < 4; ++nf) {
      f16x8 bfr = ld8(&Ps[(nf * 16 + li) * 72 + kc * 32 + g * 4]);
      s[nf] = __builtin_amdgcn_mfma_f32_16x16x32_f16(a, bfr, s[nf], 0, 0, 0);
    }
  }
#pragma unroll
  for (int nf = 0; nf < 4; ++nf) {
    int j = n0 + nf * 16 + li;
    float dv = Dm[h * TWO_L + j];
#pragma unroll
    for (int rr2 = 0; rr2 < 4; ++rr2) {
      int q = q0 + w * 16 + g * 4 + rr2;
      float val = s[nf][rr2] + dv;
      if (j < L_SEQ - q) {
        F[((size_t)bh * L_SEQ + q) * L_SEQ + q + j] = (f16)val;
      } else if (j >= TWO_L - q && q < L_SEQ - 1) {
        F[((size_t)bh * L_SEQ + q + 1) * L_SEQ + (j - TWO_L + q)] = (f16)val;
      }
    }
  }
}

// ---------------- fused attention: S^T = K.Q^T (+F, mask) -> online softmax -> O^T = V^T.P ----------------
__global__ __launch_bounds__(256) void attn_mfma(const f16* __restrict__ xh,
                                                 const f16* __restrict__ qvh,
                                                 const f16* __restrict__ vT,
                                                 const f16* __restrict__ F,
                                                 const int* __restrict__ mask,
                                                 const float* __restrict__ rr,
                                                 float* __restrict__ out) {
  __shared__ f16 Qs[64 * 72];
  __shared__ f16 Ks[64 * 72];
  __shared__ f16 Vs[64 * 72];
  int tid = threadIdx.x;
  int w = tid >> 6, lane = tid & 63, g = lane >> 4, li = lane & 15;
  int bh = blockIdx.y, b = bh >> 4, h = bh & 15;
  int q0 = blockIdx.x * 64;

  // stage Q (+ r_r_bias), f32 add then round
  {
    int r = tid >> 2, c = (tid & 3) * 16;
    const f16* src = qvh + (size_t)(b * L_SEQ + q0 + r) * 2048 + h * HD + c;
#pragma unroll
    for (int u = 0; u < 16; ++u)
      Qs[r * 72 + c + u] = (f16)((float)src[u] + rr[h * HD + c + u]);
  }

  float m_run = -1e30f, l_run = 0.f;
  f32x4 o[4];
#pragma unroll
  for (int i = 0; i < 4; ++i) o[i] = {0.f, 0.f, 0.f, 0.f};

  int qrow = q0 + w * 16 + li;          // this lane's q (col of S^T)
  const f16* Fq = F + ((size_t)bh * L_SEQ + qrow) * L_SEQ;

  int r = tid >> 2, c = (tid & 3) * 16;
  for (int k0 = 0; k0 < L_SEQ; k0 += 64) {
    __syncthreads();
    const f16* sk = xh + (size_t)(b * L_SEQ + k0 + r) * 1024 + h * HD + c;
    *(f16x8*)&Ks[r * 72 + c] = *(const f16x8*)sk;
    *(f16x8*)&Ks[r * 72 + c + 8] = *(const f16x8*)(sk + 8);
    const f16* sv2 = vT + ((size_t)bh * 64 + r) * 1024 + k0 + c;
    *(f16x8*)&Vs[r * 72 + c] = *(const f16x8*)sv2;
    *(f16x8*)&Vs[r * 72 + c + 8] = *(const f16x8*)(sv2 + 8);
    __syncthreads();

    // S^T[k][q] for 64 k x 16 q (this wave's q strip)
    f32x4 s[4];
#pragma unroll
    for (int i = 0; i < 4; ++i) s[i] = {0.f, 0.f, 0.f, 0.f};
#pragma unroll
    for (int kc = 0; kc < 2; ++kc) {
      f16x8 qb = ld8(&Qs[(w * 16 + li) * 72 + kc * 32 + g * 4]);
#pragma unroll
      for (int kf = 0; kf < 4; ++kf) {
        f16x8 ka = ld8(&Ks[(kf * 16 + li) * 72 + kc * 32 + g * 4]);
        s[kf] = __builtin_amdgcn_mfma_f32_16x16x32_f16(ka, qb, s[kf], 0, 0, 0);
      }
    }

    // add F, mask; per-lane q is fixed -> online softmax stats via 2 shfl
    float sv[16];
    float tmax = -1e30f;
#pragma unroll
    for (int kf = 0; kf < 4; ++kf) {
      f16x4 fv = *(const f16x4*)(Fq + k0 + kf * 16 + g * 4);
      const int* mp = mask + b * L_SEQ + k0 + kf * 16 + g * 4;
      int4 mv = *(const int4*)mp;
      int mm[4] = {mv.x, mv.y, mv.z, mv.w};
#pragma unroll
      for (int rr2 = 0; rr2 < 4; ++rr2) {
        float v_ = s[kf][rr2] + (float)fv[rr2];
        if (mm[rr2] == 0) v_ = -1e30f;
        sv[kf * 4 + rr2] = v_;
        tmax = fmaxf(tmax, v_);
      }
    }
    tmax = fmaxf(tmax, __shfl_xor(tmax, 16));
    tmax = fmaxf(tmax, __shfl_xor(tmax, 32));
    float mnew = fmaxf(m_run, tmax);
    float scale = __expf(m_run - mnew);
    m_run = mnew;
    l_run *= scale;
#pragma unroll
    for (int f = 0; f < 4; ++f) {
      o[f][0] *= scale; o[f][1] *= scale; o[f][2] *= scale; o[f][3] *= scale;
    }
    float pf[16];
    float lloc = 0.f;
#pragma unroll
    for (int i = 0; i < 16; ++i) { pf[i] = __expf(sv[i] - mnew); lloc += pf[i]; }
    l_run += lloc;
    f16x8 pb0, pb1;
#pragma unroll
    for (int i = 0; i < 8; ++i) { pb0[i] = (f16)pf[i]; pb1[i] = (f16)pf[8 + i]; }

    // O^T[d][q] += V^T . P
#pragma unroll
    for (int f = 0; f < 4; ++f) {
      f16x8 va0 = ld8(&Vs[(f * 16 + li) * 72 + g * 4]);
      o[f] = __builtin_amdgcn_mfma_f32_16x16x32_f16(va0, pb0, o[f], 0, 0, 0);
      f16x8 va1 = ld8(&Vs[(f * 16 + li) * 72 + 32 + g * 4]);
      o[f] = __builtin_amdgcn_mfma_f32_16x16x32_f16(va1, pb1, o[f], 0, 0, 0);
    }
  }

  float lt = l_run;
  lt += __shfl_xor(lt, 16);
  lt += __shfl_xor(lt, 32);
  float inv = 1.0f / lt;
  float* op = out + ((size_t)(b * L_SEQ + qrow)) * DM + h * HD;
#pragma unroll
  for (int f = 0; f < 4; ++f) {
    float4 res = {o[f][0] * inv, o[f][1] * inv, o[f][2] * inv, o[f][3] * inv};
    *(float4*)(op + f * 16 + g * 4) = res;
  }
}

extern "C" void kernel_launch(void* const* d_in, const int* in_sizes, int n_in,
                              void* d_out, int out_size, void* d_ws, size_t ws_size,
                              hipStream_t stream) {
  const float* x = (const float*)d_in[0];
  const int* mask = (const int*)d_in[1];
  const float* W = (const float*)d_in[2];
  const float* rr = (const float*)d_in[3];
  const float* rw = (const float*)d_in[4];
  float* out = (float*)d_out;

  float* ws = (float*)d_ws;
  float* pe = ws;                                    // 131072 f32
  float* Dm = pe + 131072;                           // 32768 f32
  f16* peh = (f16*)(Dm + 32768);                     // 131072 f16
  f16* xh = peh + 131072;                            // 2M f16
  f16* Wh = xh + 2097152;                            // 2M f16
  f16* qvh = Wh + 2097152;                           // 4M f16
  f16* vT = qvh + 4194304;                           // 2M f16
  f16* F = vT + 2097152;                             // 32M f16 (64 MB)

  cvt_kernel<<<2048, 256, 0, stream>>>(x, xh);
  cvt_kernel<<<2048, 256, 0, stream>>>(W, Wh);
  pe_kernel<<<TWO_L, HD, 0, stream>>>(pe, peh);
  dmat_kernel<<<128, 256, 0, stream>>>(rw, pe, Dm);
  fzero_kernel<<<128, 256, 0, stream>>>(F);
  qv_mfma<<<dim3(32, 32), 256, 0, stream>>>(xh, Wh, qvh, vT);
  f_gemm<<<dim3(32, 16, 32), 256, 0, stream>>>(qvh, peh, Dm, F);
  attn_mfma<<<dim3(16, 32), 256, 0, stream>>>(xh, qvh, vT, F, mask, rr, out);
}

// Round 3
// 110.085 us; speedup vs baseline: 16.2308x; 1.3957x over previous
//
#include <hip/hip_runtime.h>
#include <hip/hip_bf16.h>
#include <math.h>

#define L_SEQ 1024
#define TWO_L 2048
#define NHEAD 16
#define HD 64
#define DM 1024
#define BATCH 2

typedef _Float16 f16;
typedef _Float16 f16x4 __attribute__((ext_vector_type(4)));
typedef _Float16 f16x8 __attribute__((ext_vector_type(8)));
typedef float f32x4 __attribute__((ext_vector_type(4)));

// 8-elem f16 MFMA operand fragment: 4 contiguous halves at p, 4 at p+16
__device__ __forceinline__ f16x8 ld8(const f16* p) {
  f16x4 lo = *(const f16x4*)p;
  f16x4 hi = *(const f16x4*)(p + 16);
  f16x8 r;
  r[0] = lo[0]; r[1] = lo[1]; r[2] = lo[2]; r[3] = lo[3];
  r[4] = hi[0]; r[5] = hi[1]; r[6] = hi[2]; r[7] = hi[3];
  return r;
}

// ---------------- prep1: cvt x, cvt W, sinusoid table ----------------
__global__ __launch_bounds__(256) void prep1(const float* __restrict__ x,
                                             const float* __restrict__ W,
                                             float* __restrict__ pe,
                                             f16* __restrict__ peh,
                                             f16* __restrict__ xh,
                                             f16* __restrict__ Wh) {
  int bid = blockIdx.x, tid = threadIdx.x;
  if (bid < 2048) {
    int i = (bid * 256 + tid) * 4;
    float4 v = *(const float4*)(x + i);
    f16x4 o = {(f16)v.x, (f16)v.y, (f16)v.z, (f16)v.w};
    *(f16x4*)(xh + i) = o;
  } else if (bid < 4096) {
    int i = ((bid - 2048) * 256 + tid) * 4;
    float4 v = *(const float4*)(W + i);
    f16x4 o = {(f16)v.x, (f16)v.y, (f16)v.z, (f16)v.w};
    *(f16x4*)(Wh + i) = o;
  } else {
    int idx = (bid - 4096) * 256 + tid;   // 0..131071
    int l = idx >> 6, d = idx & 63;
    float posval = (float)(l - L_SEQ);
    float freq = expf(-(float)(d & 31) * 0.2971077539347156f);  // ln(10000)/31
    float ang = posval * freq;
    float v = (d < 32) ? sinf(ang) : cosf(ang);
    pe[idx] = v;
    peh[idx] = (f16)v;
  }
}

// ---------------- prep2: D[h][l] = rw[h].pe[l]; zero shifted diag ----------------
__global__ __launch_bounds__(256) void prep2(const float* __restrict__ rw,
                                             const float* __restrict__ pe,
                                             float* __restrict__ Dm,
                                             f16* __restrict__ F) {
  int bid = blockIdx.x, tid = threadIdx.x;
  if (bid < 128) {
    int idx = bid * 256 + tid;
    int h = idx >> 11, l = idx & (TWO_L - 1);
    float s = 0.f;
#pragma unroll
    for (int d = 0; d < HD; ++d) s = fmaf(rw[h * HD + d], pe[l * HD + d], s);
    Dm[idx] = s;
  } else {
    int idx = (bid - 128) * 256 + tid;    // bh*1024 + q
    int bh = idx >> 10, q = idx & 1023;
    if (q >= 1) F[((size_t)bh * L_SEQ + q) * L_SEQ + q - 1] = (f16)0.f;
  }
}

// ---------------- qv GEMM (2-phase async pipeline) ----------------
#define QV_STEP(T, AS, BS, CA0, CA1, CB0, CB1, NA0, NA1, NB0, NB1)             \
  {                                                                            \
    *(f16x8*)&AS[r * 72 + c] = CA0;                                            \
    *(f16x8*)&AS[r * 72 + c + 8] = CA1;                                        \
    *(f16x8*)&BS[r * 72 + c] = CB0;                                            \
    *(f16x8*)&BS[r * 72 + c + 8] = CB1;                                        \
    __syncthreads();                                                           \
    if ((T) + 1 < 16) {                                                        \
      const f16* na = ga + ((T) + 1) * 64;                                     \
      NA0 = *(const f16x8*)na;                                                 \
      NA1 = *(const f16x8*)(na + 8);                                           \
      const f16* nb = gb + ((T) + 1) * 64;                                     \
      NB0 = *(const f16x8*)nb;                                                 \
      NB1 = *(const f16x8*)(nb + 8);                                           \
    }                                                                          \
    _Pragma("unroll")                                                          \
    for (int kc = 0; kc < 2; ++kc) {                                           \
      f16x8 a = ld8(&AS[(w * 16 + li) * 72 + kc * 32 + g * 4]);                \
      _Pragma("unroll")                                                        \
      for (int nf = 0; nf < 4; ++nf) {                                         \
        f16x8 bfr = ld8(&BS[(nf * 16 + li) * 72 + kc * 32 + g * 4]);           \
        s[nf] = __builtin_amdgcn_mfma_f32_16x16x32_f16(a, bfr, s[nf], 0, 0, 0);\
      }                                                                        \
    }                                                                          \
  }

__global__ __launch_bounds__(256) void qv_mfma(const f16* __restrict__ xh,
                                               const f16* __restrict__ Wh,
                                               f16* __restrict__ qvh,
                                               f16* __restrict__ vT) {
  __shared__ f16 As0[64 * 72], As1[64 * 72];
  __shared__ f16 Bs0[64 * 72], Bs1[64 * 72];
  int tid = threadIdx.x;
  int w = tid >> 6, lane = tid & 63, g = lane >> 4, li = lane & 15;
  int m0 = blockIdx.y * 64, n0 = blockIdx.x * 64;
  int r = tid >> 2, c = (tid & 3) * 16;

  const f16* ga = xh + (size_t)(m0 + r) * 1024 + c;
  const f16* gb = Wh + (size_t)(n0 + r) * 1024 + c;
  f16x8 ca0 = *(const f16x8*)ga, ca1 = *(const f16x8*)(ga + 8);
  f16x8 cb0 = *(const f16x8*)gb, cb1 = *(const f16x8*)(gb + 8);
  f16x8 na0, na1, nb0, nb1;

  f32x4 s[4];
#pragma unroll
  for (int i = 0; i < 4; ++i) s[i] = {0.f, 0.f, 0.f, 0.f};

  for (int t = 0; t < 16; t += 2) {
    QV_STEP(t, As0, Bs0, ca0, ca1, cb0, cb1, na0, na1, nb0, nb1);
    QV_STEP(t + 1, As1, Bs1, na0, na1, nb0, nb1, ca0, ca1, cb0, cb1);
  }

#pragma unroll
  for (int nf = 0; nf < 4; ++nf) {
    int n = n0 + nf * 16 + li;
#pragma unroll
    for (int rr2 = 0; rr2 < 4; ++rr2) {
      int m = m0 + w * 16 + g * 4 + rr2;
      f16 val = (f16)s[nf][rr2];
      if (n < 1024) {
        qvh[(size_t)m * 2048 + n] = val;
      } else {
        int b_ = m >> 10, ls = m & 1023, hd = n - 1024;
        vT[((size_t)(b_ * 16 + (hd >> 6)) * 64 + (hd & 63)) * 1024 + ls] = val;
      }
    }
  }
}

// ---------------- F GEMM: B_[q][j] = q.pe_j + D[h][j], scatter to shifted F ----------------
__global__ __launch_bounds__(256) void f_gemm(const f16* __restrict__ qvh,
                                              const f16* __restrict__ peh,
                                              const float* __restrict__ Dm,
                                              f16* __restrict__ F) {
  __shared__ f16 Qs[64 * 72];
  __shared__ f16 Ps[64 * 72];
  int tid = threadIdx.x;
  int w = tid >> 6, lane = tid & 63, g = lane >> 4, li = lane & 15;
  int bh = blockIdx.z, b = bh >> 4, h = bh & 15;
  int q0 = blockIdx.y * 64, n0 = blockIdx.x * 64;
  int r = tid >> 2, c = (tid & 3) * 16;

  // early bias loads
  float dvv[4];
#pragma unroll
  for (int nf = 0; nf < 4; ++nf) dvv[nf] = Dm[h * TWO_L + n0 + nf * 16 + li];

  const f16* sq = qvh + (size_t)(b * L_SEQ + q0 + r) * 2048 + h * HD + c;
  *(f16x8*)&Qs[r * 72 + c] = *(const f16x8*)sq;
  *(f16x8*)&Qs[r * 72 + c + 8] = *(const f16x8*)(sq + 8);
  const f16* sp = peh + (size_t)(n0 + r) * HD + c;
  *(f16x8*)&Ps[r * 72 + c] = *(const f16x8*)sp;
  *(f16x8*)&Ps[r * 72 + c + 8] = *(const f16x8*)(sp + 8);
  __syncthreads();

  f32x4 s[4];
#pragma unroll
  for (int i = 0; i < 4; ++i) s[i] = {0.f, 0.f, 0.f, 0.f};
#pragma unroll
  for (int kc = 0; kc < 2; ++kc) {
    f16x8 a = ld8(&Qs[(w * 16 + li) * 72 + kc * 32 + g * 4]);
#pragma unroll
    for (int nf = 0; nf < 4; ++nf) {
      f16x8 bfr = ld8(&Ps[(nf * 16 + li) * 72 + kc * 32 + g * 4]);
      s[nf] = __builtin_amdgcn_mfma_f32_16x16x32_f16(a, bfr, s[nf], 0, 0, 0);
    }
  }
#pragma unroll
  for (int nf = 0; nf < 4; ++nf) {
    int j = n0 + nf * 16 + li;
#pragma unroll
    for (int rr2 = 0; rr2 < 4; ++rr2) {
      int q = q0 + w * 16 + g * 4 + rr2;
      float val = s[nf][rr2] + dvv[nf];
      if (j < L_SEQ - q) {
        F[((size_t)bh * L_SEQ + q) * L_SEQ + q + j] = (f16)val;
      } else if (j >= TWO_L - q && q < L_SEQ - 1) {
        F[((size_t)bh * L_SEQ + q + 1) * L_SEQ + (j - TWO_L + q)] = (f16)val;
      }
    }
  }
}

// ---------------- fused attention (2-phase async pipeline, dbuf LDS) ----------------
#define ATTN_STEP(T, KS, VS, CK0, CK1, CV0, CV1, NK0, NK1, NV0, NV1)           \
  {                                                                            \
    const int k0 = (T) * 64;                                                   \
    *(f16x8*)&KS[r * 72 + c] = CK0;                                            \
    *(f16x8*)&KS[r * 72 + c + 8] = CK1;                                        \
    *(f16x8*)&VS[r * 72 + c] = CV0;                                            \
    *(f16x8*)&VS[r * 72 + c + 8] = CV1;                                        \
    __syncthreads();                                                           \
    if ((T) + 1 < 16) {                                                        \
      const f16* nk = gk + (size_t)((T) + 1) * 64 * 1024;                      \
      NK0 = *(const f16x8*)nk;                                                 \
      NK1 = *(const f16x8*)(nk + 8);                                           \
      const f16* nv = gv + ((T) + 1) * 64;                                     \
      NV0 = *(const f16x8*)nv;                                                 \
      NV1 = *(const f16x8*)(nv + 8);                                           \
    }                                                                          \
    f16x4 fvv[4];                                                              \
    _Pragma("unroll")                                                          \
    for (int kf = 0; kf < 4; ++kf)                                             \
      fvv[kf] = *(const f16x4*)(Fq + k0 + kf * 16 + g * 4);                    \
    f32x4 s[4];                                                                \
    _Pragma("unroll")                                                          \
    for (int i = 0; i < 4; ++i) s[i] = {0.f, 0.f, 0.f, 0.f};                   \
    __builtin_amdgcn_s_setprio(1);                                             \
    _Pragma("unroll")                                                          \
    for (int kc = 0; kc < 2; ++kc) {                                           \
      f16x8 qb = ld8(&Qs[(w * 16 + li) * 72 + kc * 32 + g * 4]);               \
      _Pragma("unroll")                                                        \
      for (int kf = 0; kf < 4; ++kf) {                                         \
        f16x8 ka = ld8(&KS[(kf * 16 + li) * 72 + kc * 32 + g * 4]);            \
        s[kf] = __builtin_amdgcn_mfma_f32_16x16x32_f16(ka, qb, s[kf], 0, 0, 0);\
      }                                                                        \
    }                                                                          \
    __builtin_amdgcn_s_setprio(0);                                             \
    float sv[16];                                                              \
    float tmax = -1e30f;                                                       \
    _Pragma("unroll")                                                          \
    for (int kf = 0; kf < 4; ++kf) {                                           \
      _Pragma("unroll")                                                        \
      for (int rr2 = 0; rr2 < 4; ++rr2) {                                      \
        float v_ = s[kf][rr2] + (float)fvv[kf][rr2] +                          \
                   Ms[k0 + kf * 16 + g * 4 + rr2];                             \
        sv[kf * 4 + rr2] = v_;                                                 \
        tmax = fmaxf(tmax, v_);                                                \
      }                                                                        \
    }                                                                          \
    tmax = fmaxf(tmax, __shfl_xor(tmax, 16));                                  \
    tmax = fmaxf(tmax, __shfl_xor(tmax, 32));                                  \
    float mnew = fmaxf(m_run, tmax);                                           \
    float scale = __expf(m_run - mnew);                                        \
    m_run = mnew;                                                              \
    l_run *= scale;                                                            \
    _Pragma("unroll")                                                          \
    for (int f = 0; f < 4; ++f) {                                              \
      o[f][0] *= scale; o[f][1] *= scale; o[f][2] *= scale; o[f][3] *= scale;  \
    }                                                                          \
    float pf[16];                                                              \
    float lloc = 0.f;                                                          \
    _Pragma("unroll")                                                          \
    for (int i = 0; i < 16; ++i) { pf[i] = __expf(sv[i] - mnew); lloc += pf[i]; } \
    l_run += lloc;                                                             \
    f16x8 pb0, pb1;                                                            \
    _Pragma("unroll")                                                          \
    for (int i = 0; i < 8; ++i) { pb0[i] = (f16)pf[i]; pb1[i] = (f16)pf[8 + i]; } \
    __builtin_amdgcn_s_setprio(1);                                             \
    _Pragma("unroll")                                                          \
    for (int f = 0; f < 4; ++f) {                                              \
      f16x8 va0 = ld8(&VS[(f * 16 + li) * 72 + g * 4]);                        \
      o[f] = __builtin_amdgcn_mfma_f32_16x16x32_f16(va0, pb0, o[f], 0, 0, 0);  \
      f16x8 va1 = ld8(&VS[(f * 16 + li) * 72 + 32 + g * 4]);                   \
      o[f] = __builtin_amdgcn_mfma_f32_16x16x32_f16(va1, pb1, o[f], 0, 0, 0);  \
    }                                                                          \
    __builtin_amdgcn_s_setprio(0);                                             \
  }

__global__ __launch_bounds__(256) void attn_mfma(const f16* __restrict__ xh,
                                                 const f16* __restrict__ qvh,
                                                 const f16* __restrict__ vT,
                                                 const f16* __restrict__ F,
                                                 const int* __restrict__ mask,
                                                 const float* __restrict__ rr,
                                                 float* __restrict__ out) {
  __shared__ f16 Qs[64 * 72];
  __shared__ f16 Ks0[64 * 72], Ks1[64 * 72];
  __shared__ f16 Vs0[64 * 72], Vs1[64 * 72];
  __shared__ float Ms[L_SEQ];
  int tid = threadIdx.x;
  int w = tid >> 6, lane = tid & 63, g = lane >> 4, li = lane & 15;
  int bh = blockIdx.y, b = bh >> 4, h = bh & 15;
  int q0 = blockIdx.x * 64;
  int r = tid >> 2, c = (tid & 3) * 16;

  // additive mask vector
#pragma unroll
  for (int i = 0; i < 4; ++i) {
    int k = tid + i * 256;
    Ms[k] = mask[b * L_SEQ + k] ? 0.f : -1e30f;
  }
  // Q (+r_r_bias)
  {
    const f16* src = qvh + (size_t)(b * L_SEQ + q0 + r) * 2048 + h * HD + c;
#pragma unroll
    for (int u = 0; u < 16; ++u)
      Qs[r * 72 + c + u] = (f16)((float)src[u] + rr[h * HD + c + u]);
  }

  const f16* gk = xh + (size_t)(b * L_SEQ + r) * 1024 + h * HD + c;
  const f16* gv = vT + ((size_t)bh * 64 + r) * 1024 + c;
  f16x8 cka = *(const f16x8*)gk, ckb = *(const f16x8*)(gk + 8);
  f16x8 cva = *(const f16x8*)gv, cvb = *(const f16x8*)(gv + 8);
  f16x8 nka, nkb, nva, nvb;

  float m_run = -1e30f, l_run = 0.f;
  f32x4 o[4];
#pragma unroll
  for (int i = 0; i < 4; ++i) o[i] = {0.f, 0.f, 0.f, 0.f};

  int qrow = q0 + w * 16 + li;
  const f16* Fq = F + ((size_t)bh * L_SEQ + qrow) * L_SEQ;

  for (int t = 0; t < 16; t += 2) {
    ATTN_STEP(t, Ks0, Vs0, cka, ckb, cva, cvb, nka, nkb, nva, nvb);
    ATTN_STEP(t + 1, Ks1, Vs1, nka, nkb, nva, nvb, cka, ckb, cva, cvb);
  }

  float lt = l_run;
  lt += __shfl_xor(lt, 16);
  lt += __shfl_xor(lt, 32);
  float inv = 1.0f / lt;
  float* op = out + ((size_t)(b * L_SEQ + qrow)) * DM + h * HD;
#pragma unroll
  for (int f = 0; f < 4; ++f) {
    float4 res = {o[f][0] * inv, o[f][1] * inv, o[f][2] * inv, o[f][3] * inv};
    *(float4*)(op + f * 16 + g * 4) = res;
  }
}

extern "C" void kernel_launch(void* const* d_in, const int* in_sizes, int n_in,
                              void* d_out, int out_size, void* d_ws, size_t ws_size,
                              hipStream_t stream) {
  const float* x = (const float*)d_in[0];
  const int* mask = (const int*)d_in[1];
  const float* W = (const float*)d_in[2];
  const float* rr = (const float*)d_in[3];
  const float* rw = (const float*)d_in[4];
  float* out = (float*)d_out;

  float* ws = (float*)d_ws;
  float* pe = ws;                                    // 131072 f32
  float* Dm = pe + 131072;                           // 32768 f32
  f16* peh = (f16*)(Dm + 32768);                     // 131072 f16
  f16* xh = peh + 131072;                            // 2M f16
  f16* Wh = xh + 2097152;                            // 2M f16
  f16* qvh = Wh + 2097152;                           // 4M f16
  f16* vT = qvh + 4194304;                           // 2M f16
  f16* F = vT + 2097152;                             // 32M f16 (64 MB)

  prep1<<<4608, 256, 0, stream>>>(x, W, pe, peh, xh, Wh);
  prep2<<<256, 256, 0, stream>>>(rw, pe, Dm, F);
  qv_mfma<<<dim3(32, 32), 256, 0, stream>>>(xh, Wh, qvh, vT);
  f_gemm<<<dim3(32, 16, 32), 256, 0, stream>>>(qvh, peh, Dm, F);
  attn_mfma<<<dim3(16, 32), 256, 0, stream>>>(xh, qvh, vT, F, mask, rr, out);
}